// Round 1
// baseline (2145.033 us; speedup 1.0000x reference)
//
#include <hip/hip_runtime.h>
#include <hip/hip_bf16.h>

// ---------------------------------------------------------------------------
// Conv (3x3, stride 2, pad 1) + bias + relu, with per-channel sum/sumsq stats.
// One block per (b, co). Threads grid-stride over output pixels.
// ---------------------------------------------------------------------------
__global__ __launch_bounds__(256) void conv_relu_stats(
    const float* __restrict__ x, const float* __restrict__ w,
    const float* __restrict__ bias, float* __restrict__ y,
    float* __restrict__ stats, int Cin, int H, int W)
{
  const int Ho = H >> 1, Wo = W >> 1;
  const int bc = blockIdx.x;
  const int b = bc / 24, co = bc % 24;
  const int tid = threadIdx.x;
  __shared__ float wsm[216];           // up to 24*9
  const int nw = Cin * 9;
  for (int i = tid; i < nw; i += 256) wsm[i] = w[co * nw + i];
  __syncthreads();
  const float bv = bias[co];
  float bsum = 0.f, bsq = 0.f;
  const int n = Ho * Wo;
  for (int p = tid; p < n; p += 256) {
    const int oh = p / Wo, ow = p - oh * Wo;
    float acc = bv;
    const int ih0 = oh * 2 - 1, iw0 = ow * 2 - 1;
    for (int ci = 0; ci < Cin; ++ci) {
      const float* xp = x + ((size_t)(b * Cin + ci)) * H * W;
      const float* wp = wsm + ci * 9;
      #pragma unroll
      for (int r = 0; r < 3; ++r) {
        const int ih = ih0 + r;
        if ((unsigned)ih < (unsigned)H) {
          #pragma unroll
          for (int s = 0; s < 3; ++s) {
            const int iw = iw0 + s;
            if ((unsigned)iw < (unsigned)W)
              acc += xp[ih * W + iw] * wp[r * 3 + s];
          }
        }
      }
    }
    const float v = fmaxf(acc, 0.f);
    y[(((size_t)b * 24 + co) * Ho + oh) * Wo + ow] = v;
    bsum += v; bsq += v * v;
  }
  // wave reduce (wave64), then cross-wave via LDS, one atomic pair per block
  #pragma unroll
  for (int off = 32; off > 0; off >>= 1) {
    bsum += __shfl_down(bsum, off, 64);
    bsq  += __shfl_down(bsq,  off, 64);
  }
  __shared__ float rs[4], rq[4];
  const int wv = tid >> 6, ln = tid & 63;
  if (ln == 0) { rs[wv] = bsum; rq[wv] = bsq; }
  __syncthreads();
  if (tid == 0) {
    atomicAdd(&stats[co],      rs[0] + rs[1] + rs[2] + rs[3]);
    atomicAdd(&stats[24 + co], rq[0] + rq[1] + rq[2] + rq[3]);
  }
}

// ---------------------------------------------------------------------------
// BatchNorm apply (in place): x = (x - mean) * rsqrt(var+eps) * gamma + beta
// ---------------------------------------------------------------------------
__global__ __launch_bounds__(256) void bn_apply(
    float* __restrict__ y, const float* __restrict__ stats,
    const float* __restrict__ gamma, const float* __restrict__ beta,
    int HoWo, int total)
{
  const float cnt = (float)(64 * HoWo);
  for (int idx = blockIdx.x * 256 + threadIdx.x; idx < total;
       idx += gridDim.x * 256) {
    const int c = (idx / HoWo) % 24;
    const float m = stats[c] / cnt;
    const float v = stats[24 + c] / cnt - m * m;
    const float sc = rsqrtf(v + 1e-5f) * gamma[c];
    const float sh = beta[c] - m * sc;
    y[idx] = y[idx] * sc + sh;
  }
}

// ---------------------------------------------------------------------------
// Build A = o @ Wi, B = o @ Wj   (o = [24 channels of x4, row, col])
// One block per (b, p); thread t computes output column t.
// ---------------------------------------------------------------------------
__global__ __launch_bounds__(256) void build_ab(
    const float* __restrict__ x4, const float* __restrict__ gw1,
    float* __restrict__ A, float* __restrict__ Bm)
{
  const int bp = blockIdx.x;           // b*64 + p
  const int b = bp >> 6, p = bp & 63;
  const int t = threadIdx.x;
  __shared__ float o[26];
  if (t < 24)       o[t]  = x4[(((size_t)b * 24 + t) * 8 + (p >> 3)) * 8 + (p & 7)];
  else if (t == 24) o[24] = (float)(p >> 3);
  else if (t == 25) o[25] = (float)(p & 7);
  __syncthreads();
  float a = 0.f, bb2 = 0.f;
  #pragma unroll
  for (int c = 0; c < 26; ++c) {
    a   += o[c] * gw1[c * 256 + t];
    bb2 += o[c] * gw1[(26 + c) * 256 + t];
  }
  A[(size_t)bp * 256 + t]  = a;
  Bm[(size_t)bp * 256 + t] = bb2;
}

__global__ __launch_bounds__(256) void build_cq(
    const float* __restrict__ qst, const float* __restrict__ gw1,
    const float* __restrict__ gb1, float* __restrict__ Cq)
{
  const int b = blockIdx.x, t = threadIdx.x;
  float a = gb1[t];
  #pragma unroll
  for (int c = 0; c < 11; ++c) a += qst[b * 11 + c] * gw1[(52 + c) * 256 + t];
  Cq[b * 256 + t] = a;
}

// ---------------------------------------------------------------------------
// Pair MLP: for block (b,j), rows i=0..63 (2 tiles of 32):
//   h1 = relu(A[b,i]+B[b,j]+Cq[b]); h2..h4 = relu(h @ W + bias); gsum += h4
// LDS: hA/hB 32x256 f32 (32 KB each) + W chunk 16x256 (16 KB) = 80 KB.
// Thread (tm=tid/32, tn=tid%32) computes rows tm*4..+3, cols tn*8..+7.
// ---------------------------------------------------------------------------
#define MT 32
#define KC 16

__global__ __launch_bounds__(256) void pair_mlp(
    const float* __restrict__ A, const float* __restrict__ Bm,
    const float* __restrict__ Cq,
    const float* __restrict__ W2, const float* __restrict__ b2,
    const float* __restrict__ W3, const float* __restrict__ b3,
    const float* __restrict__ W4, const float* __restrict__ b4,
    float* __restrict__ Gpart)
{
  const int bj = blockIdx.x;
  const int b = bj >> 6;
  const int tid = threadIdx.x;
  const int tm = tid >> 5, tn = tid & 31;
  __shared__ float hA[MT * 256];
  __shared__ float hB[MT * 256];
  __shared__ float Wc[KC * 256];
  float gsum[8];
  #pragma unroll
  for (int c = 0; c < 8; ++c) gsum[c] = 0.f;

  const float* Brow = Bm + (size_t)bj * 256;
  const float* Cqb  = Cq + (size_t)b * 256;

  for (int half = 0; half < 2; ++half) {
    // ---- build h1 into hA
    #pragma unroll
    for (int r = 0; r < 4; ++r) {
      const int m = tm * 4 + r;
      const int i = half * 32 + m;
      const float* Arow = A + ((size_t)(b * 64 + i)) * 256;
      #pragma unroll
      for (int cc = 0; cc < 2; ++cc) {
        const int c = tn * 8 + cc * 4;
        const float4 av = *(const float4*)(Arow + c);
        const float4 bv = *(const float4*)(Brow + c);
        const float4 cv = *(const float4*)(Cqb + c);
        float4 h;
        h.x = fmaxf(av.x + bv.x + cv.x, 0.f);
        h.y = fmaxf(av.y + bv.y + cv.y, 0.f);
        h.z = fmaxf(av.z + bv.z + cv.z, 0.f);
        h.w = fmaxf(av.w + bv.w + cv.w, 0.f);
        *(float4*)(&hA[m * 256 + c]) = h;
      }
    }
    __syncthreads();

    const float* hin = hA;
    float* hout = hB;
    for (int layer = 0; layer < 3; ++layer) {
      const float* W    = layer == 0 ? W2 : (layer == 1 ? W3 : W4);
      const float* bias = layer == 0 ? b2 : (layer == 1 ? b3 : b4);
      float acc[4][8];
      {
        const float4 bv0 = *(const float4*)(bias + tn * 8);
        const float4 bv1 = *(const float4*)(bias + tn * 8 + 4);
        #pragma unroll
        for (int r = 0; r < 4; ++r) {
          acc[r][0] = bv0.x; acc[r][1] = bv0.y; acc[r][2] = bv0.z; acc[r][3] = bv0.w;
          acc[r][4] = bv1.x; acc[r][5] = bv1.y; acc[r][6] = bv1.z; acc[r][7] = bv1.w;
        }
      }
      for (int kc = 0; kc < 256; kc += KC) {
        // stage W[kc..kc+KC) rows into LDS (1024 float4 / 256 threads)
        const float4* Wg = (const float4*)(W + (size_t)kc * 256);
        float4* Wl = (float4*)Wc;
        #pragma unroll
        for (int v = 0; v < (KC * 64) / 256; ++v)
          Wl[v * 256 + tid] = Wg[v * 256 + tid];
        __syncthreads();
        #pragma unroll
        for (int k4 = 0; k4 < KC; k4 += 4) {
          float4 hv[4];
          #pragma unroll
          for (int r = 0; r < 4; ++r)
            hv[r] = *(const float4*)(hin + (tm * 4 + r) * 256 + kc + k4);
          #pragma unroll
          for (int kk = 0; kk < 4; ++kk) {
            const float4 w0 = *(const float4*)(Wc + (k4 + kk) * 256 + tn * 8);
            const float4 w1 = *(const float4*)(Wc + (k4 + kk) * 256 + tn * 8 + 4);
            #pragma unroll
            for (int r = 0; r < 4; ++r) {
              const float h = kk == 0 ? hv[r].x : kk == 1 ? hv[r].y
                            : kk == 2 ? hv[r].z : hv[r].w;
              acc[r][0] += h * w0.x; acc[r][1] += h * w0.y;
              acc[r][2] += h * w0.z; acc[r][3] += h * w0.w;
              acc[r][4] += h * w1.x; acc[r][5] += h * w1.y;
              acc[r][6] += h * w1.z; acc[r][7] += h * w1.w;
            }
          }
        }
        __syncthreads();
      }
      if (layer < 2) {
        #pragma unroll
        for (int r = 0; r < 4; ++r) {
          const int m = tm * 4 + r;
          float4 h0, h1;
          h0.x = fmaxf(acc[r][0], 0.f); h0.y = fmaxf(acc[r][1], 0.f);
          h0.z = fmaxf(acc[r][2], 0.f); h0.w = fmaxf(acc[r][3], 0.f);
          h1.x = fmaxf(acc[r][4], 0.f); h1.y = fmaxf(acc[r][5], 0.f);
          h1.z = fmaxf(acc[r][6], 0.f); h1.w = fmaxf(acc[r][7], 0.f);
          *(float4*)(hout + m * 256 + tn * 8)     = h0;
          *(float4*)(hout + m * 256 + tn * 8 + 4) = h1;
        }
        __syncthreads();
        const float* tmp = hin; hin = hout; hout = (float*)tmp;
      } else {
        #pragma unroll
        for (int r = 0; r < 4; ++r)
          #pragma unroll
          for (int c = 0; c < 8; ++c)
            gsum[c] += fmaxf(acc[r][c], 0.f);
      }
    }
  }
  // reduce gsum over tm (8 row-groups) and emit per-(b,j) partial
  __syncthreads();
  #pragma unroll
  for (int c = 0; c < 8; ++c) hA[tm * 256 + tn * 8 + c] = gsum[c];
  __syncthreads();
  float s = 0.f;
  #pragma unroll
  for (int m = 0; m < 8; ++m) s += hA[m * 256 + tid];
  Gpart[(size_t)bj * 256 + tid] = s;
}

__global__ __launch_bounds__(256) void reduce_g(
    const float* __restrict__ Gpart, float* __restrict__ g)
{
  const int b = blockIdx.x, t = threadIdx.x;
  float s = 0.f;
  for (int j = 0; j < 64; ++j) s += Gpart[((size_t)(b * 64 + j)) * 256 + t];
  g[b * 256 + t] = s;
}

// ---------------------------------------------------------------------------
// f-network + softmax. One block per batch element.
// ---------------------------------------------------------------------------
__global__ __launch_bounds__(256) void fnet(
    const float* __restrict__ g,
    const float* __restrict__ fw1, const float* __restrict__ fb1,
    const float* __restrict__ fw2, const float* __restrict__ fb2,
    const float* __restrict__ fw3, const float* __restrict__ fb3,
    float* __restrict__ out)
{
  const int b = blockIdx.x, t = threadIdx.x;
  __shared__ float s0[256], s1[256], lg[10];
  s0[t] = g[b * 256 + t];
  __syncthreads();
  float acc = fb1[t];
  for (int k = 0; k < 256; ++k) acc += s0[k] * fw1[k * 256 + t];
  s1[t] = fmaxf(acc, 0.f);
  __syncthreads();
  acc = fb2[t];
  for (int k = 0; k < 256; ++k) acc += s1[k] * fw2[k * 256 + t];
  s0[t] = fmaxf(acc, 0.f);
  __syncthreads();
  if (t < 10) {
    float a = fb3[t];
    for (int k = 0; k < 256; ++k) a += s0[k] * fw3[k * 10 + t];
    lg[t] = a;
  }
  __syncthreads();
  if (t == 0) {
    float m = lg[0];
    for (int c = 1; c < 10; ++c) m = fmaxf(m, lg[c]);
    float e[10], sum = 0.f;
    for (int c = 0; c < 10; ++c) { e[c] = expf(lg[c] - m); sum += e[c]; }
    const float inv = 1.f / sum;
    for (int c = 0; c < 10; ++c) out[b * 10 + c] = e[c] * inv;
  }
}

// ---------------------------------------------------------------------------
extern "C" void kernel_launch(void* const* d_in, const int* in_sizes, int n_in,
                              void* d_out, int out_size, void* d_ws, size_t ws_size,
                              hipStream_t stream)
{
  const float* img = (const float*)d_in[0];
  const float* qst = (const float*)d_in[1];
  const float* cw[4] = {(const float*)d_in[2],  (const float*)d_in[6],
                        (const float*)d_in[10], (const float*)d_in[14]};
  const float* cb[4] = {(const float*)d_in[3],  (const float*)d_in[7],
                        (const float*)d_in[11], (const float*)d_in[15]};
  const float* bg[4] = {(const float*)d_in[4],  (const float*)d_in[8],
                        (const float*)d_in[12], (const float*)d_in[16]};
  const float* bb[4] = {(const float*)d_in[5],  (const float*)d_in[9],
                        (const float*)d_in[13], (const float*)d_in[17]};
  const float* gw1 = (const float*)d_in[18];
  const float* gb1 = (const float*)d_in[19];
  const float* gw2 = (const float*)d_in[20];
  const float* gb2 = (const float*)d_in[21];
  const float* gw3 = (const float*)d_in[22];
  const float* gb3 = (const float*)d_in[23];
  const float* gw4 = (const float*)d_in[24];
  const float* gb4 = (const float*)d_in[25];
  const float* fw1 = (const float*)d_in[26];
  const float* fb1 = (const float*)d_in[27];
  const float* fw2 = (const float*)d_in[28];
  const float* fb2 = (const float*)d_in[29];
  const float* fw3 = (const float*)d_in[30];
  const float* fb3 = (const float*)d_in[31];
  float* out = (float*)d_out;

  float* ws    = (float*)d_ws;
  float* x1    = ws;                  // 64*24*64*64 = 6291456
  float* x2    = x1 + 6291456;        // 1572864
  float* x3    = x2 + 1572864;        // 393216
  float* x4    = x3 + 393216;         // 98304
  float* Abuf  = x4 + 98304;          // 1048576
  float* Bbuf  = Abuf + 1048576;      // 1048576
  float* Cqb   = Bbuf + 1048576;      // 16384
  float* Gpart = Cqb + 16384;         // 1048576
  float* gbuf  = Gpart + 1048576;     // 16384
  float* stats = gbuf + 16384;        // 4 * 48

  hipMemsetAsync(stats, 0, 192 * sizeof(float), stream);

  conv_relu_stats<<<1536, 256, 0, stream>>>(img, cw[0], cb[0], x1, stats +   0, 3, 128, 128);
  bn_apply<<<4096, 256, 0, stream>>>(x1, stats +   0, bg[0], bb[0], 64 * 64, 6291456);
  conv_relu_stats<<<1536, 256, 0, stream>>>(x1,  cw[1], cb[1], x2, stats +  48, 24, 64, 64);
  bn_apply<<<2048, 256, 0, stream>>>(x2, stats +  48, bg[1], bb[1], 32 * 32, 1572864);
  conv_relu_stats<<<1536, 256, 0, stream>>>(x2,  cw[2], cb[2], x3, stats +  96, 24, 32, 32);
  bn_apply<<<1024, 256, 0, stream>>>(x3, stats +  96, bg[2], bb[2], 16 * 16, 393216);
  conv_relu_stats<<<1536, 256, 0, stream>>>(x3,  cw[3], cb[3], x4, stats + 144, 24, 16, 16);
  bn_apply<<<384, 256, 0, stream>>>(x4, stats + 144, bg[3], bb[3], 8 * 8, 98304);

  build_ab<<<4096, 256, 0, stream>>>(x4, gw1, Abuf, Bbuf);
  build_cq<<<64, 256, 0, stream>>>(qst, gw1, gb1, Cqb);

  pair_mlp<<<4096, 256, 0, stream>>>(Abuf, Bbuf, Cqb, gw2, gb2, gw3, gb3,
                                     gw4, gb4, Gpart);
  reduce_g<<<64, 256, 0, stream>>>(Gpart, gbuf);
  fnet<<<64, 256, 0, stream>>>(gbuf, fw1, fb1, fw2, fb2, fw3, fb3, out);
}

// Round 2
// 845.667 us; speedup vs baseline: 2.5365x; 2.5365x over previous
//
#include <hip/hip_runtime.h>
#include <hip/hip_bf16.h>

typedef __attribute__((ext_vector_type(8))) short bf16x8_t;
typedef __attribute__((ext_vector_type(4))) float f32x4_t;

__device__ __forceinline__ unsigned bfr(float x) {
  unsigned u = __builtin_bit_cast(unsigned, x);
  return (u + 0x7fffu + ((u >> 16) & 1u)) >> 16;
}
__device__ __forceinline__ unsigned pk2(float lo, float hi) {
  return bfr(lo) | (bfr(hi) << 16);
}

// ---------------------------------------------------------------------------
// Conv (3x3, stride 2, pad 1) + bias + relu, with per-channel sum/sumsq stats.
// ---------------------------------------------------------------------------
__global__ __launch_bounds__(256) void conv_relu_stats(
    const float* __restrict__ x, const float* __restrict__ w,
    const float* __restrict__ bias, float* __restrict__ y,
    float* __restrict__ stats, int Cin, int H, int W)
{
  const int Ho = H >> 1, Wo = W >> 1;
  const int bc = blockIdx.x;
  const int b = bc / 24, co = bc % 24;
  const int tid = threadIdx.x;
  __shared__ float wsm[216];
  const int nw = Cin * 9;
  for (int i = tid; i < nw; i += 256) wsm[i] = w[co * nw + i];
  __syncthreads();
  const float bv = bias[co];
  float bsum = 0.f, bsq = 0.f;
  const int n = Ho * Wo;
  for (int p = tid; p < n; p += 256) {
    const int oh = p / Wo, ow = p - oh * Wo;
    float acc = bv;
    const int ih0 = oh * 2 - 1, iw0 = ow * 2 - 1;
    for (int ci = 0; ci < Cin; ++ci) {
      const float* xp = x + ((size_t)(b * Cin + ci)) * H * W;
      const float* wp = wsm + ci * 9;
      #pragma unroll
      for (int r = 0; r < 3; ++r) {
        const int ih = ih0 + r;
        if ((unsigned)ih < (unsigned)H) {
          #pragma unroll
          for (int s = 0; s < 3; ++s) {
            const int iw = iw0 + s;
            if ((unsigned)iw < (unsigned)W)
              acc += xp[ih * W + iw] * wp[r * 3 + s];
          }
        }
      }
    }
    const float v = fmaxf(acc, 0.f);
    y[(((size_t)b * 24 + co) * Ho + oh) * Wo + ow] = v;
    bsum += v; bsq += v * v;
  }
  #pragma unroll
  for (int off = 32; off > 0; off >>= 1) {
    bsum += __shfl_down(bsum, off, 64);
    bsq  += __shfl_down(bsq,  off, 64);
  }
  __shared__ float rs[4], rq[4];
  const int wv = tid >> 6, ln = tid & 63;
  if (ln == 0) { rs[wv] = bsum; rq[wv] = bsq; }
  __syncthreads();
  if (tid == 0) {
    atomicAdd(&stats[co],      rs[0] + rs[1] + rs[2] + rs[3]);
    atomicAdd(&stats[24 + co], rq[0] + rq[1] + rq[2] + rq[3]);
  }
}

__global__ __launch_bounds__(256) void bn_apply(
    float* __restrict__ y, const float* __restrict__ stats,
    const float* __restrict__ gamma, const float* __restrict__ beta,
    int HoWo, int total)
{
  const float cnt = (float)(64 * HoWo);
  for (int idx = blockIdx.x * 256 + threadIdx.x; idx < total;
       idx += gridDim.x * 256) {
    const int c = (idx / HoWo) % 24;
    const float m = stats[c] / cnt;
    const float v = stats[24 + c] / cnt - m * m;
    const float sc = rsqrtf(v + 1e-5f) * gamma[c];
    const float sh = beta[c] - m * sc;
    y[idx] = y[idx] * sc + sh;
  }
}

// ---------------------------------------------------------------------------
// Build A = o @ Wi, B = o @ Wj, Cq = qst @ Wq + gb1  (all fp32)
// ---------------------------------------------------------------------------
__global__ __launch_bounds__(256) void build_ab(
    const float* __restrict__ x4, const float* __restrict__ gw1,
    float* __restrict__ A, float* __restrict__ Bm)
{
  const int bp = blockIdx.x;
  const int b = bp >> 6, p = bp & 63;
  const int t = threadIdx.x;
  __shared__ float o[26];
  if (t < 24)       o[t]  = x4[(((size_t)b * 24 + t) * 8 + (p >> 3)) * 8 + (p & 7)];
  else if (t == 24) o[24] = (float)(p >> 3);
  else if (t == 25) o[25] = (float)(p & 7);
  __syncthreads();
  float a = 0.f, bb2 = 0.f;
  #pragma unroll
  for (int c = 0; c < 26; ++c) {
    a   += o[c] * gw1[c * 256 + t];
    bb2 += o[c] * gw1[(26 + c) * 256 + t];
  }
  A[(size_t)bp * 256 + t]  = a;
  Bm[(size_t)bp * 256 + t] = bb2;
}

__global__ __launch_bounds__(256) void build_cq(
    const float* __restrict__ qst, const float* __restrict__ gw1,
    const float* __restrict__ gb1, float* __restrict__ Cq)
{
  const int b = blockIdx.x, t = threadIdx.x;
  float a = gb1[t];
  #pragma unroll
  for (int c = 0; c < 11; ++c) a += qst[b * 11 + c] * gw1[(52 + c) * 256 + t];
  Cq[b * 256 + t] = a;
}

// ---------------------------------------------------------------------------
// Transpose-convert W (fp32 [k][n]) -> Wt (bf16 [n][k]). Grid 64, block 256.
// ---------------------------------------------------------------------------
__global__ __launch_bounds__(256) void wt_convert(
    const float* __restrict__ W, __hip_bfloat16* __restrict__ wt)
{
  __shared__ float ts[32][33];
  const int k0 = (blockIdx.x & 7) * 32, n0 = (blockIdx.x >> 3) * 32;
  const int t = threadIdx.x;
  const int r = t >> 3, c4 = (t & 7) * 4;
  const float4 v = *(const float4*)(W + (size_t)(k0 + r) * 256 + n0 + c4);
  ts[r][c4 + 0] = v.x; ts[r][c4 + 1] = v.y;
  ts[r][c4 + 2] = v.z; ts[r][c4 + 3] = v.w;
  __syncthreads();
  uint2 o;
  o.x = pk2(ts[c4 + 0][r], ts[c4 + 1][r]);
  o.y = pk2(ts[c4 + 2][r], ts[c4 + 3][r]);
  *(uint2*)((unsigned short*)wt + (size_t)(n0 + r) * 256 + k0 + c4) = o;
}

// ---------------------------------------------------------------------------
// Pair MLP via MFMA (swapped operands: A-frag = Wt rows, B-frag = h rows).
// Block: 512 thr / 8 waves, 128 rows x 256 cols. Wave tile 64 cols x 64 rows.
// LDS: h[128][256] bf16 XOR-swizzled (64KB) + Wt dbuf [2][256][40] bf16
// (80B padded rows, 40KB) + gpart (2KB).
// ---------------------------------------------------------------------------
#define WT_STRIDE 40   // bf16 elements per padded Wt row (80 B)

__global__ __launch_bounds__(512) void pair_mfma(
    const float* __restrict__ A, const float* __restrict__ Bm,
    const float* __restrict__ Cq,
    const __hip_bfloat16* __restrict__ wt2, const float* __restrict__ b2,
    const __hip_bfloat16* __restrict__ wt3, const float* __restrict__ b3,
    const __hip_bfloat16* __restrict__ wt4, const float* __restrict__ b4,
    float* __restrict__ g)
{
  __shared__ __align__(16) unsigned short hsm[128 * 256];
  __shared__ __align__(16) unsigned short wsm[2][256 * WT_STRIDE];
  __shared__ float gpart[2][256];

  const int tid = threadIdx.x;
  const int bid = blockIdx.x;
  const int b = bid >> 5, local = bid & 31;
  const int lane = tid & 63, w = tid >> 6;
  const int cg = w & 3, rg = w >> 2;       // col-group (64 cols), row-group (64 rows)
  const int l15 = lane & 15, l4 = lane >> 4;

  char* hbase = (char*)hsm;

  // ---- build h1 = relu(A_i + B_j + Cq) in bf16, swizzled
  {
    const int m = tid >> 2, seg = tid & 3;
    const int p = local * 128 + m;
    const int i = p & 63, jj = p >> 6;
    const float* Ar = A  + (size_t)(b * 64 + i)  * 256 + seg * 64;
    const float* Br = Bm + (size_t)(b * 64 + jj) * 256 + seg * 64;
    const float* Cr = Cq + (size_t)b * 256 + seg * 64;
    #pragma unroll
    for (int it = 0; it < 8; ++it) {
      const float4 a0 = *(const float4*)(Ar + it * 8);
      const float4 a1 = *(const float4*)(Ar + it * 8 + 4);
      const float4 b0 = *(const float4*)(Br + it * 8);
      const float4 b1 = *(const float4*)(Br + it * 8 + 4);
      const float4 c0 = *(const float4*)(Cr + it * 8);
      const float4 c1 = *(const float4*)(Cr + it * 8 + 4);
      uint4 pk;
      pk.x = pk2(fmaxf(a0.x + b0.x + c0.x, 0.f), fmaxf(a0.y + b0.y + c0.y, 0.f));
      pk.y = pk2(fmaxf(a0.z + b0.z + c0.z, 0.f), fmaxf(a0.w + b0.w + c0.w, 0.f));
      pk.z = pk2(fmaxf(a1.x + b1.x + c1.x, 0.f), fmaxf(a1.y + b1.y + c1.y, 0.f));
      pk.w = pk2(fmaxf(a1.z + b1.z + c1.z, 0.f), fmaxf(a1.w + b1.w + c1.w, 0.f));
      const int kb = seg * 128 + it * 16;
      *(uint4*)(hbase + (size_t)m * 512 + (kb ^ ((m & 7) << 4))) = pk;
    }
  }

  const __hip_bfloat16* wts[3] = {wt2, wt3, wt4};
  const float* bs[3] = {b2, b3, b4};

  // staging helper indices: thread stages 2x16B chunks of the 16KB Wt chunk
  const int sn0 = tid >> 2, ss = tid & 3;          // n row, 16B slot
  const int sn1 = sn0 + 128;

  for (int layer = 0; layer < 3; ++layer) {
    const unsigned short* wtg = (const unsigned short*)wts[layer];
    // ---- acc init with bias
    f32x4_t acc[4][4];
    #pragma unroll
    for (int a = 0; a < 4; ++a) {
      const float4 bv = *(const float4*)(bs[layer] + cg * 64 + a * 16 + l4 * 4);
      #pragma unroll
      for (int t = 0; t < 4; ++t) {
        acc[a][t][0] = bv.x; acc[a][t][1] = bv.y;
        acc[a][t][2] = bv.z; acc[a][t][3] = bv.w;
      }
    }
    // ---- stage chunk 0
    {
      const uint4 s0 = *(const uint4*)(wtg + (size_t)sn0 * 256 + ss * 8);
      const uint4 s1 = *(const uint4*)(wtg + (size_t)sn1 * 256 + ss * 8);
      char* wb = (char*)wsm[0];
      *(uint4*)(wb + sn0 * 80 + ss * 16) = s0;
      *(uint4*)(wb + sn1 * 80 + ss * 16) = s1;
    }
    __syncthreads();

    for (int ks = 0; ks < 8; ++ks) {
      uint4 p0, p1;
      const bool pref = ks < 7;
      if (pref) {
        p0 = *(const uint4*)(wtg + (size_t)sn0 * 256 + (ks + 1) * 32 + ss * 8);
        p1 = *(const uint4*)(wtg + (size_t)sn1 * 256 + (ks + 1) * 32 + ss * 8);
      }
      // B-frags: 4 h rows (this wave's row tiles), contiguous 16B swizzled
      bf16x8_t bf[4];
      #pragma unroll
      for (int t = 0; t < 4; ++t) {
        const int row = rg * 64 + t * 16 + l15;
        const int kb = ks * 64 + l4 * 16;
        bf[t] = *(const bf16x8_t*)(hbase + (size_t)row * 512 + (kb ^ ((row & 7) << 4)));
      }
      const char* wrd = (const char*)wsm[ks & 1];
      #pragma unroll
      for (int a = 0; a < 4; ++a) {
        const bf16x8_t af = *(const bf16x8_t*)(wrd + (cg * 64 + a * 16 + l15) * 80 + l4 * 16);
        #pragma unroll
        for (int t = 0; t < 4; ++t)
          acc[a][t] = __builtin_amdgcn_mfma_f32_16x16x32_bf16(af, bf[t], acc[a][t], 0, 0, 0);
      }
      if (pref) {
        char* wb = (char*)wsm[(ks + 1) & 1];
        *(uint4*)(wb + sn0 * 80 + ss * 16) = p0;
        *(uint4*)(wb + sn1 * 80 + ss * 16) = p1;
      }
      __syncthreads();
    }

    if (layer < 2) {
      // ---- write back relu(h_next) as bf16, 8B per (a,t)
      #pragma unroll
      for (int a = 0; a < 4; ++a) {
        #pragma unroll
        for (int t = 0; t < 4; ++t) {
          const int row = rg * 64 + t * 16 + l15;
          const int n0 = cg * 64 + a * 16 + l4 * 4;
          uint2 v;
          v.x = pk2(fmaxf(acc[a][t][0], 0.f), fmaxf(acc[a][t][1], 0.f));
          v.y = pk2(fmaxf(acc[a][t][2], 0.f), fmaxf(acc[a][t][3], 0.f));
          *(uint2*)(hbase + (size_t)row * 512 + ((n0 * 2) ^ ((row & 7) << 4))) = v;
        }
      }
      // next layer's stage+barrier orders these writes before any h read
    } else {
      // ---- column sums of relu(h4) over this block's 128 rows
      #pragma unroll
      for (int a = 0; a < 4; ++a) {
        f32x4_t s;
        s[0] = s[1] = s[2] = s[3] = 0.f;
        #pragma unroll
        for (int t = 0; t < 4; ++t) {
          s[0] += fmaxf(acc[a][t][0], 0.f);
          s[1] += fmaxf(acc[a][t][1], 0.f);
          s[2] += fmaxf(acc[a][t][2], 0.f);
          s[3] += fmaxf(acc[a][t][3], 0.f);
        }
        #pragma unroll
        for (int d = 1; d < 16; d <<= 1) {
          s[0] += __shfl_xor(s[0], d, 64);
          s[1] += __shfl_xor(s[1], d, 64);
          s[2] += __shfl_xor(s[2], d, 64);
          s[3] += __shfl_xor(s[3], d, 64);
        }
        if (l15 == 0)
          *(f32x4_t*)(&gpart[rg][cg * 64 + a * 16 + l4 * 4]) = s;
      }
      __syncthreads();
      if (tid < 256)
        atomicAdd(&g[(size_t)b * 256 + tid], gpart[0][tid] + gpart[1][tid]);
    }
  }
}

// ---------------------------------------------------------------------------
// f-network + softmax. One block per batch element.
// ---------------------------------------------------------------------------
__global__ __launch_bounds__(256) void fnet(
    const float* __restrict__ g,
    const float* __restrict__ fw1, const float* __restrict__ fb1,
    const float* __restrict__ fw2, const float* __restrict__ fb2,
    const float* __restrict__ fw3, const float* __restrict__ fb3,
    float* __restrict__ out)
{
  const int b = blockIdx.x, t = threadIdx.x;
  __shared__ float s0[256], s1[256], lg[10];
  s0[t] = g[b * 256 + t];
  __syncthreads();
  float acc = fb1[t];
  for (int k = 0; k < 256; ++k) acc += s0[k] * fw1[k * 256 + t];
  s1[t] = fmaxf(acc, 0.f);
  __syncthreads();
  acc = fb2[t];
  for (int k = 0; k < 256; ++k) acc += s1[k] * fw2[k * 256 + t];
  s0[t] = fmaxf(acc, 0.f);
  __syncthreads();
  if (t < 10) {
    float a = fb3[t];
    for (int k = 0; k < 256; ++k) a += s0[k] * fw3[k * 10 + t];
    lg[t] = a;
  }
  __syncthreads();
  if (t == 0) {
    float m = lg[0];
    for (int c = 1; c < 10; ++c) m = fmaxf(m, lg[c]);
    float e[10], sum = 0.f;
    for (int c = 0; c < 10; ++c) { e[c] = expf(lg[c] - m); sum += e[c]; }
    const float inv = 1.f / sum;
    for (int c = 0; c < 10; ++c) out[b * 10 + c] = e[c] * inv;
  }
}

// ---------------------------------------------------------------------------
extern "C" void kernel_launch(void* const* d_in, const int* in_sizes, int n_in,
                              void* d_out, int out_size, void* d_ws, size_t ws_size,
                              hipStream_t stream)
{
  const float* img = (const float*)d_in[0];
  const float* qst = (const float*)d_in[1];
  const float* cw[4] = {(const float*)d_in[2],  (const float*)d_in[6],
                        (const float*)d_in[10], (const float*)d_in[14]};
  const float* cb[4] = {(const float*)d_in[3],  (const float*)d_in[7],
                        (const float*)d_in[11], (const float*)d_in[15]};
  const float* bg[4] = {(const float*)d_in[4],  (const float*)d_in[8],
                        (const float*)d_in[12], (const float*)d_in[16]};
  const float* bb[4] = {(const float*)d_in[5],  (const float*)d_in[9],
                        (const float*)d_in[13], (const float*)d_in[17]};
  const float* gw1 = (const float*)d_in[18];
  const float* gb1 = (const float*)d_in[19];
  const float* gw2 = (const float*)d_in[20];
  const float* gb2 = (const float*)d_in[21];
  const float* gw3 = (const float*)d_in[22];
  const float* gb3 = (const float*)d_in[23];
  const float* gw4 = (const float*)d_in[24];
  const float* gb4 = (const float*)d_in[25];
  const float* fw1 = (const float*)d_in[26];
  const float* fb1 = (const float*)d_in[27];
  const float* fw2 = (const float*)d_in[28];
  const float* fb2 = (const float*)d_in[29];
  const float* fw3 = (const float*)d_in[30];
  const float* fb3 = (const float*)d_in[31];
  float* out = (float*)d_out;

  float* ws    = (float*)d_ws;
  float* x1    = ws;                  // 6291456
  float* x2    = x1 + 6291456;        // 1572864
  float* x3    = x2 + 1572864;        // 393216
  float* x4    = x3 + 393216;         // 98304
  float* Abuf  = x4 + 98304;          // 1048576
  float* Bbuf  = Abuf + 1048576;      // 1048576
  float* Cqb   = Bbuf + 1048576;      // 16384
  float* gbuf  = Cqb + 16384;         // 16384
  float* stats = gbuf + 16384;        // 192
  __hip_bfloat16* wtb = (__hip_bfloat16*)(stats + 192);
  __hip_bfloat16* wt2 = wtb;
  __hip_bfloat16* wt3 = wtb + 65536;
  __hip_bfloat16* wt4 = wtb + 131072;

  hipMemsetAsync(gbuf, 0, (16384 + 192) * sizeof(float), stream);

  conv_relu_stats<<<1536, 256, 0, stream>>>(img, cw[0], cb[0], x1, stats +   0, 3, 128, 128);
  bn_apply<<<4096, 256, 0, stream>>>(x1, stats +   0, bg[0], bb[0], 64 * 64, 6291456);
  conv_relu_stats<<<1536, 256, 0, stream>>>(x1,  cw[1], cb[1], x2, stats +  48, 24, 64, 64);
  bn_apply<<<2048, 256, 0, stream>>>(x2, stats +  48, bg[1], bb[1], 32 * 32, 1572864);
  conv_relu_stats<<<1536, 256, 0, stream>>>(x2,  cw[2], cb[2], x3, stats +  96, 24, 32, 32);
  bn_apply<<<1024, 256, 0, stream>>>(x3, stats +  96, bg[2], bb[2], 16 * 16, 393216);
  conv_relu_stats<<<1536, 256, 0, stream>>>(x3,  cw[3], cb[3], x4, stats + 144, 24, 16, 16);
  bn_apply<<<384, 256, 0, stream>>>(x4, stats + 144, bg[3], bb[3], 8 * 8, 98304);

  build_ab<<<4096, 256, 0, stream>>>(x4, gw1, Abuf, Bbuf);
  build_cq<<<64, 256, 0, stream>>>(qst, gw1, gb1, Cqb);

  wt_convert<<<64, 256, 0, stream>>>(gw2, wt2);
  wt_convert<<<64, 256, 0, stream>>>(gw3, wt3);
  wt_convert<<<64, 256, 0, stream>>>(gw4, wt4);

  pair_mfma<<<2048, 512, 0, stream>>>(Abuf, Bbuf, Cqb, wt2, gb2, wt3, gb3,
                                      wt4, gb4, gbuf);
  fnet<<<64, 256, 0, stream>>>(gbuf, fw1, fb1, fw2, fb2, fw3, fb3, out);
}